// Round 16
// baseline (962.988 us; speedup 1.0000x reference)
//
#include <hip/hip_runtime.h>
#include <hip/hip_cooperative_groups.h>
#include <math.h>

namespace cg = cooperative_groups;

// GCN 2-layer, pull-based (CSR by dst via counting sort), no float atomics.
//   fW1 = feat@W1 (bf16-packed); h = relu(segsum(fW1[src])+b1);
//   p = h@W2; out = softmax(segsum(p[src])+b2)
// R15: hist returning-atomic floor (~65us) is measured-invariant across 7
//   structural variants -> stop attacking it. Remaining gap 201 vs ~181us of
//   kernel time = 8 dispatch gaps + memset. Fix: ONE cooperative mega-kernel
//   (1024 blocks guaranteed resident via __launch_bounds__(256,4)), phases
//   separated by grid.sync(), bodies = R13's proven kernels. Fallback to the
//   R13 multi-kernel path if cooperative launch fails.

#define SCAN_B 1024
#define PAD    16
#define GRID_B 1024

__device__ __forceinline__ unsigned f2bf(float x) {
    unsigned u = __float_as_uint(x);
    return (u + 0x7fff + ((u >> 16) & 1)) >> 16;   // RNE, low 16 bits
}

// ================= shared device bodies =================

__device__ __forceinline__ void prep_body(
    const float4* __restrict__ feat4, const float* __restrict__ W1,
    unsigned* __restrict__ fW1b, const int* __restrict__ dst,
    int* __restrict__ counts, int* __restrict__ rank,
    int n_nodes, int E, int ntiles, int vb, int tid, float (*ft)[64])
{
    int lane = tid & 63, w = tid >> 6;
    int e = vb * 256 + tid;
    bool he = (e < E);
    int d = he ? dst[e] : 0;

    bool tile = (vb < ntiles);
    int base = vb * 16;
    float4 wc[16];
    if (tile) {
#pragma unroll
        for (int k4 = 0; k4 < 16; ++k4)
            wc[k4] = make_float4(W1[(k4 * 4 + 0) * 64 + lane],
                                 W1[(k4 * 4 + 1) * 64 + lane],
                                 W1[(k4 * 4 + 2) * 64 + lane],
                                 W1[(k4 * 4 + 3) * 64 + lane]);
        int rr = tid >> 4, c = tid & 15;
        int gn = base + rr;
        ((float4*)ft[rr])[c] = (gn < n_nodes) ? feat4[(size_t)gn * 16 + c]
                                              : make_float4(0.f, 0.f, 0.f, 0.f);
    }
    __syncthreads();                      // staging vmem drained here

    int r = 0;                             // atomic AFTER drain (R13 mechanism)
    if (he) r = atomicAdd(&counts[(size_t)d * PAD], 1);

    if (tile) {
        for (int i = 0; i < 4; ++i) {
            int rr = w * 4 + i;
            int gn = base + rr;
            if (gn < n_nodes) {
                float acc = 0.f;
                const float4* row4 = (const float4*)ft[rr];
#pragma unroll
                for (int k4 = 0; k4 < 16; ++k4) {
                    float4 f = row4[k4];
                    acc = fmaf(f.x, wc[k4].x,
                          fmaf(f.y, wc[k4].y,
                          fmaf(f.z, wc[k4].z,
                          fmaf(f.w, wc[k4].w, acc))));
                }
                unsigned hb = f2bf(acc);
                unsigned other = __shfl_xor((int)hb, 1, 64);
                if (!(lane & 1))
                    fW1b[(size_t)gn * 32 + (lane >> 1)] = hb | (other << 16);
            }
        }
    }
    if (he) rank[e] = r;
}

__device__ __forceinline__ void fill_body(
    const int* __restrict__ src, const int* __restrict__ dst,
    const int* __restrict__ rank, const int* __restrict__ offs,
    int* __restrict__ ssort, int E, long g)
{
    long e0 = g * 4;
    if (e0 >= E) return;
    if (e0 + 3 < E) {
        int4 d = ((const int4*)dst)[g];
        int4 sr = ((const int4*)src)[g];
        int4 r = ((const int4*)rank)[g];
        ssort[offs[d.x] + r.x] = sr.x;
        ssort[offs[d.y] + r.y] = sr.y;
        ssort[offs[d.z] + r.z] = sr.z;
        ssort[offs[d.w] + r.w] = sr.w;
    } else {
        for (long e = e0; e < E; ++e)
            ssort[offs[dst[e]] + rank[e]] = src[e];
    }
}

__device__ __forceinline__ void layer1_body(
    const unsigned* __restrict__ fW1b, const int* __restrict__ offs,
    const int* __restrict__ ssort, const float* __restrict__ b1,
    const float* __restrict__ W2, float* __restrict__ p,
    int n_nodes, int node, int lane)
{
    if (node >= n_nodes) return;
    int beg = offs[node], end = offs[node + 1];
    int half = lane >> 5;
    int sl = lane & 31;
    float ax = 0.f, ay = 0.f;
    int k = beg + half;
    for (; k + 14 < end; k += 16) {
        int s0 = ssort[k],      s1 = ssort[k + 2],  s2 = ssort[k + 4],  s3 = ssort[k + 6];
        int s4 = ssort[k + 8],  s5 = ssort[k + 10], s6 = ssort[k + 12], s7 = ssort[k + 14];
        unsigned u0 = fW1b[(size_t)s0 * 32 + sl];
        unsigned u1 = fW1b[(size_t)s1 * 32 + sl];
        unsigned u2 = fW1b[(size_t)s2 * 32 + sl];
        unsigned u3 = fW1b[(size_t)s3 * 32 + sl];
        unsigned u4 = fW1b[(size_t)s4 * 32 + sl];
        unsigned u5 = fW1b[(size_t)s5 * 32 + sl];
        unsigned u6 = fW1b[(size_t)s6 * 32 + sl];
        unsigned u7 = fW1b[(size_t)s7 * 32 + sl];
        ax += (__uint_as_float(u0 << 16) + __uint_as_float(u1 << 16))
            + (__uint_as_float(u2 << 16) + __uint_as_float(u3 << 16))
            + (__uint_as_float(u4 << 16) + __uint_as_float(u5 << 16))
            + (__uint_as_float(u6 << 16) + __uint_as_float(u7 << 16));
        ay += (__uint_as_float(u0 & 0xffff0000u) + __uint_as_float(u1 & 0xffff0000u))
            + (__uint_as_float(u2 & 0xffff0000u) + __uint_as_float(u3 & 0xffff0000u))
            + (__uint_as_float(u4 & 0xffff0000u) + __uint_as_float(u5 & 0xffff0000u))
            + (__uint_as_float(u6 & 0xffff0000u) + __uint_as_float(u7 & 0xffff0000u));
    }
    for (; k + 6 < end; k += 8) {
        int s0 = ssort[k], s1 = ssort[k + 2], s2 = ssort[k + 4], s3 = ssort[k + 6];
        unsigned u0 = fW1b[(size_t)s0 * 32 + sl];
        unsigned u1 = fW1b[(size_t)s1 * 32 + sl];
        unsigned u2 = fW1b[(size_t)s2 * 32 + sl];
        unsigned u3 = fW1b[(size_t)s3 * 32 + sl];
        ax += (__uint_as_float(u0 << 16) + __uint_as_float(u1 << 16))
            + (__uint_as_float(u2 << 16) + __uint_as_float(u3 << 16));
        ay += (__uint_as_float(u0 & 0xffff0000u) + __uint_as_float(u1 & 0xffff0000u))
            + (__uint_as_float(u2 & 0xffff0000u) + __uint_as_float(u3 & 0xffff0000u));
    }
    for (; k < end; k += 2) {
        unsigned u = fW1b[(size_t)ssort[k] * 32 + sl];
        ax += __uint_as_float(u << 16);
        ay += __uint_as_float(u & 0xffff0000u);
    }
    ax += __shfl_xor(ax, 32, 64);
    ay += __shfl_xor(ay, 32, 64);
    float am = __shfl(ax, lane >> 1, 64);
    float bm = __shfl(ay, lane >> 1, 64);
    float acc = (lane & 1) ? bm : am;
    // tail: b1 + relu + compact dense2
    float h = fmaxf(acc + b1[lane], 0.f);
    int j = lane & 15, ks = lane >> 4;
    float pp = 0.f;
#pragma unroll
    for (int i = 0; i < 16; ++i) {
        int kk = ks * 16 + i;
        float hk = __shfl(h, kk, 64);
        pp = fmaf(hk, W2[kk * 16 + j], pp);
    }
    pp += __shfl_xor(pp, 16, 64);
    pp += __shfl_xor(pp, 32, 64);
    if (ks == 0) p[(size_t)node * 16 + j] = pp;
}

__device__ __forceinline__ void layer2_body(
    const float4* __restrict__ p4, const int* __restrict__ offs,
    const int* __restrict__ ssort, const float* __restrict__ b2,
    float* __restrict__ out, int n_nodes, int node, int lane)
{
    if (node >= n_nodes) return;
    int slot = lane >> 2;
    int q = lane & 3;
    int beg = offs[node], end = offs[node + 1];
    float a0 = 0.f, a1 = 0.f, a2 = 0.f, a3 = 0.f;
    int k = beg + slot;
    for (; k + 16 < end; k += 32) {
        int s0 = ssort[k], s1 = ssort[k + 16];
        float4 v0 = p4[(size_t)s0 * 4 + q];
        float4 v1 = p4[(size_t)s1 * 4 + q];
        a0 += v0.x + v1.x;
        a1 += v0.y + v1.y;
        a2 += v0.z + v1.z;
        a3 += v0.w + v1.w;
    }
    for (; k < end; k += 16) {
        float4 v = p4[(size_t)ssort[k] * 4 + q];
        a0 += v.x; a1 += v.y; a2 += v.z; a3 += v.w;
    }
#pragma unroll
    for (int dd = 4; dd <= 32; dd <<= 1) {
        a0 += __shfl_xor(a0, dd, 64);
        a1 += __shfl_xor(a1, dd, 64);
        a2 += __shfl_xor(a2, dd, 64);
        a3 += __shfl_xor(a3, dd, 64);
    }
    float4 bb = ((const float4*)b2)[q];
    float v0 = a0 + bb.x, v1 = a1 + bb.y, v2 = a2 + bb.z, v3 = a3 + bb.w;
    float m = fmaxf(fmaxf(v0, v1), fmaxf(v2, v3));
    m = fmaxf(m, __shfl_xor(m, 1, 64));
    m = fmaxf(m, __shfl_xor(m, 2, 64));
    float e0 = __expf(v0 - m), e1 = __expf(v1 - m);
    float e2 = __expf(v2 - m), e3 = __expf(v3 - m);
    float s = (e0 + e1) + (e2 + e3);
    s += __shfl_xor(s, 1, 64);
    s += __shfl_xor(s, 2, 64);
    if (slot == 0) {
        float inv = 1.f / s;
        float4 o; o.x = e0 * inv; o.y = e1 * inv; o.z = e2 * inv; o.w = e3 * inv;
        ((float4*)out)[(size_t)node * 4 + q] = o;
    }
}

// ================= cooperative mega-kernel =================

__global__ __launch_bounds__(256, 4) void mega_kernel(
    const float4* __restrict__ feat4, const float* __restrict__ W1,
    const float* __restrict__ b1, const float* __restrict__ W2,
    const float* __restrict__ b2, const int* __restrict__ src,
    const int* __restrict__ dst, unsigned* __restrict__ fW1b,
    int* __restrict__ counts, int* __restrict__ offs, int* __restrict__ bsums,
    int* __restrict__ ssort, int* __restrict__ rank, float* __restrict__ p,
    float* __restrict__ out, int N, int E)
{
    cg::grid_group grid = cg::this_grid();
    __shared__ float ft[16][64];          // prep staging (4KB)
    __shared__ int   ldsi[256];           // scan scratch (1KB)
    int tid = threadIdx.x, bid = blockIdx.x;
    int lane = tid & 63, w = tid >> 6;

    // ---- phase 0: zero counts ----
    for (long i = (long)bid * 256 + tid; i < (long)N * PAD; i += (long)GRID_B * 256)
        counts[i] = 0;
    grid.sync();

    // ---- phase 1: prep (fw1 tile + hist per virtual block) ----
    int histBlocks = (E + 255) / 256;
    int ntiles = (N + 15) / 16;
    int NV = histBlocks > ntiles ? histBlocks : ntiles;
    for (int vb = bid; vb < NV; vb += GRID_B) {
        __syncthreads();                  // previous iteration done with ft
        prep_body(feat4, W1, fW1b, dst, counts, rank, N, E, ntiles, vb, tid, ft);
    }
    grid.sync();

    // ---- phase 2: chunk scan (1024 nodes/chunk, 4 per thread) ----
    int nb = (N + 1023) / 1024;
    for (int ch = bid; ch < nb; ch += GRID_B) {
        int i0 = ch * 1024 + tid * 4;
        int c0 = (i0 + 0 < N) ? counts[(size_t)(i0 + 0) * PAD] : 0;
        int c1 = (i0 + 1 < N) ? counts[(size_t)(i0 + 1) * PAD] : 0;
        int c2 = (i0 + 2 < N) ? counts[(size_t)(i0 + 2) * PAD] : 0;
        int c3 = (i0 + 3 < N) ? counts[(size_t)(i0 + 3) * PAD] : 0;
        int s = c0 + c1 + c2 + c3;
        __syncthreads();
        ldsi[tid] = s;
        __syncthreads();
        for (int off = 1; off < 256; off <<= 1) {
            int t = (tid >= off) ? ldsi[tid - off] : 0;
            __syncthreads();
            ldsi[tid] += t;
            __syncthreads();
        }
        int excl = ldsi[tid] - s;
        if (i0 + 0 < N) offs[i0 + 0] = excl;
        if (i0 + 1 < N) offs[i0 + 1] = excl + c0;
        if (i0 + 2 < N) offs[i0 + 2] = excl + c0 + c1;
        if (i0 + 3 < N) offs[i0 + 3] = excl + c0 + c1 + c2;
        if (tid == 255) bsums[ch] = ldsi[255];
    }
    grid.sync();

    // ---- phase 3: bsums prefix (nb<=256) + apply ----
    {
        int v = (tid < nb) ? bsums[tid] : 0;
        __syncthreads();
        ldsi[tid] = v;
        __syncthreads();
        for (int off = 1; off < 256; off <<= 1) {
            int t = (tid >= off) ? ldsi[tid - off] : 0;
            __syncthreads();
            ldsi[tid] += t;
            __syncthreads();
        }
        int ex = ldsi[tid] - v;
        __syncthreads();
        ldsi[tid] = ex;
        __syncthreads();
    }
    for (long i = (long)bid * 256 + tid; i <= (long)N; i += (long)GRID_B * 256) {
        if (i < N) offs[i] += ldsi[i >> 10];
        else offs[N] = E;
    }
    grid.sync();

    // ---- phase 4: fill ----
    long ng = ((long)E + 3) / 4;
    for (long g = (long)bid * 256 + tid; g < ng; g += (long)GRID_B * 256)
        fill_body(src, dst, rank, offs, ssort, E, g);
    grid.sync();

    // ---- phase 5: layer1 ----
    int nb1 = (N + 3) / 4;
    for (int vb = bid; vb < nb1; vb += GRID_B)
        layer1_body(fW1b, offs, ssort, b1, W2, p, N, vb * 4 + w, lane);
    grid.sync();

    // ---- phase 6: layer2 ----
    for (int vb = bid; vb < nb1; vb += GRID_B)
        layer2_body((const float4*)p, offs, ssort, b2, out, N, vb * 4 + w, lane);
}

// ================= fallback multi-kernel path (R13) =================

__global__ __launch_bounds__(256) void prep_kernel(
    const float4* __restrict__ feat4, const float* __restrict__ W1,
    unsigned* __restrict__ fW1b, const int* __restrict__ dst,
    int* __restrict__ counts, int* __restrict__ rank, int n_nodes, int E, int ntiles)
{
    __shared__ float ft[16][64];
    prep_body(feat4, W1, fW1b, dst, counts, rank, n_nodes, E, ntiles,
              blockIdx.x, threadIdx.x, ft);
}

__global__ void scan_phaseA(const int* __restrict__ counts, int* __restrict__ excl,
                            int* __restrict__ blocksums, int n) {
    __shared__ int lds[SCAN_B];
    int tid = threadIdx.x;
    int i = blockIdx.x * SCAN_B + tid;
    int v = (i < n) ? counts[(size_t)i * PAD] : 0;
    lds[tid] = v;
    __syncthreads();
    for (int off = 1; off < SCAN_B; off <<= 1) {
        int t = (tid >= off) ? lds[tid - off] : 0;
        __syncthreads();
        lds[tid] += t;
        __syncthreads();
    }
    if (i < n) excl[i] = lds[tid] - v;
    if (tid == SCAN_B - 1) blocksums[blockIdx.x] = lds[SCAN_B - 1];
}

__global__ void scan_phaseB(int* blocksums, int nb) {
    __shared__ int lds[SCAN_B];
    int tid = threadIdx.x;
    int v = (tid < nb) ? blocksums[tid] : 0;
    lds[tid] = v;
    __syncthreads();
    for (int off = 1; off < SCAN_B; off <<= 1) {
        int t = (tid >= off) ? lds[tid - off] : 0;
        __syncthreads();
        lds[tid] += t;
        __syncthreads();
    }
    if (tid < nb) blocksums[tid] = lds[tid] - v;
}

__global__ void scan_phaseC(int* __restrict__ offs, const int* __restrict__ blocksums,
                            int n, int E) {
    int i = blockIdx.x * blockDim.x + threadIdx.x;
    if (i < n) offs[i] += blocksums[i / SCAN_B];
    else if (i == n) offs[n] = E;
}

__global__ void fill_rank_kernel(const int* __restrict__ src, const int* __restrict__ dst,
                                 const int* __restrict__ rank, const int* __restrict__ offs,
                                 int* __restrict__ ssort, int E) {
    long g = (long)blockIdx.x * 256 + threadIdx.x;
    if (g * 4 < E) fill_body(src, dst, rank, offs, ssort, E, g);
}

__global__ __launch_bounds__(256) void layer1_kernel(
    const unsigned* __restrict__ fW1b, const int* __restrict__ offs,
    const int* __restrict__ ssort, const float* __restrict__ b1,
    const float* __restrict__ W2, float* __restrict__ p, int n_nodes)
{
    layer1_body(fW1b, offs, ssort, b1, W2, p, n_nodes,
                blockIdx.x * 4 + (threadIdx.x >> 6), threadIdx.x & 63);
}

__global__ __launch_bounds__(256) void layer2_kernel(
    const float4* __restrict__ p4, const int* __restrict__ offs,
    const int* __restrict__ ssort, const float* __restrict__ b2,
    float* __restrict__ out, int n_nodes)
{
    layer2_body(p4, offs, ssort, b2, out, n_nodes,
                blockIdx.x * 4 + (threadIdx.x >> 6), threadIdx.x & 63);
}

// ================= host =================

extern "C" void kernel_launch(void* const* d_in, const int* in_sizes, int n_in,
                              void* d_out, int out_size, void* d_ws, size_t ws_size,
                              hipStream_t stream) {
    const float* feat = (const float*)d_in[0];
    const float* W1   = (const float*)d_in[1];
    const float* b1   = (const float*)d_in[2];
    const float* W2   = (const float*)d_in[3];
    const float* b2   = (const float*)d_in[4];
    const int*   src  = (const int*)d_in[5];
    const int*   dst  = (const int*)d_in[6];

    int N = in_sizes[0] / 64;
    int E = in_sizes[5];

    // layout (ints): counts 16N (aliased by p 16N after scan) | fW1b 32N |
    //                offs N+1 | bsums SCAN_B | ssort E | rank E
    int*      counts = (int*)d_ws;
    float*    p      = (float*)d_ws;
    unsigned* fW1b   = (unsigned*)(counts + (size_t)N * PAD);
    int*      offs   = (int*)(fW1b + (size_t)N * 32);
    int*      bsums  = offs + N + 1;
    int*      ssort  = bsums + SCAN_B;
    int*      rank   = ssort + E;
    float*    out    = (float*)d_out;

    const float4* feat4 = (const float4*)feat;

    // ---- try cooperative mega-kernel ----
    void* args[] = {
        (void*)&feat4, (void*)&W1, (void*)&b1, (void*)&W2, (void*)&b2,
        (void*)&src, (void*)&dst, (void*)&fW1b, (void*)&counts, (void*)&offs,
        (void*)&bsums, (void*)&ssort, (void*)&rank, (void*)&p, (void*)&out,
        (void*)&N, (void*)&E
    };
    hipError_t st = hipLaunchCooperativeKernel((void*)mega_kernel,
                                               dim3(GRID_B), dim3(256),
                                               args, 0, stream);
    if (st == hipSuccess) return;

    // ---- fallback: R13 multi-kernel path ----
    int nb = (N + SCAN_B - 1) / SCAN_B;
    int histBlocks = (E + 255) / 256;
    int ntiles = (N + 15) / 16;
    int prepGrid = histBlocks > ntiles ? histBlocks : ntiles;

    hipMemsetAsync(counts, 0, (size_t)N * PAD * sizeof(int), stream);
    prep_kernel<<<prepGrid, 256, 0, stream>>>(feat4, W1, fW1b, dst, counts, rank, N, E, ntiles);
    scan_phaseA<<<nb, SCAN_B, 0, stream>>>(counts, offs, bsums, N);
    scan_phaseB<<<1, SCAN_B, 0, stream>>>(bsums, nb);
    scan_phaseC<<<(N + 1 + 255) / 256, 256, 0, stream>>>(offs, bsums, N, E);
    fill_rank_kernel<<<(E + 1023) / 1024, 256, 0, stream>>>(src, dst, rank, offs, ssort, E);
    layer1_kernel<<<(N + 3) / 4, 256, 0, stream>>>(fW1b, offs, ssort, b1, W2, p, N);
    layer2_kernel<<<(N + 3) / 4, 256, 0, stream>>>((const float4*)p, offs, ssort, b2, out, N);
}

// Round 17
// 200.857 us; speedup vs baseline: 4.7944x; 4.7944x over previous
//
#include <hip/hip_runtime.h>
#include <math.h>

// GCN 2-layer, pull-based (CSR by dst via counting sort), no float atomics.
// Algebra: segsum commutes with right-matmul -> both matmuls hoisted:
//   fW1 = feat@W1 (one pass, bf16-packed)
//   h   = relu(segsum(fW1[src]) + b1)
//   p   = h@W2 (compact per-node) ; out = softmax(segsum(p[src]) + b2)
// R16: R15's cooperative mega-kernel was 4.8x WORSE (FETCH 80->403MB, VALU 6%):
//   1024-block grid-stride destroyed per-phase grid shaping + L2 locality.
//   Reverted to the proven R13 multi-kernel structure (201us). Micro-fusion:
//   scan_phaseB folded into phaseC (each block redundantly prefixes the 98
//   bsums in LDS) -- one fewer dispatch. Known floors: prep ~68us (1.6M
//   returning atomics @ 24.6G/s, invariant across 7 structural probes),
//   layer1/2 latency-bound gathers.

#define SCAN_B 1024
#define PAD    16     // counts[node*PAD]: one node per 64B line

__device__ __forceinline__ unsigned f2bf(float x) {
    unsigned u = __float_as_uint(x);
    return (u + 0x7fff + ((u >> 16) & 1)) >> 16;   // RNE, low 16 bits
}

// ---- fused prep: every block: one 16-node fw1 tile + hist(256 edges) ----
__global__ __launch_bounds__(256) void prep_kernel(
    const float4* __restrict__ feat4, const float* __restrict__ W1,
    unsigned* __restrict__ fW1b, const int* __restrict__ dst,
    int* __restrict__ counts, int* __restrict__ rank,
    int n_nodes, int E, int ntiles)
{
    __shared__ float ft[16][64];          // 4 KB feat tile
    int tid = threadIdx.x, bid = blockIdx.x;
    int lane = tid & 63, w = tid >> 6;

    int e = bid * 256 + tid;
    bool he = (e < E);
    int d = he ? dst[e] : 0;              // plain load, early

    bool tile = (bid < ntiles);
    int base = bid * 16;
    float4 wc[16];
    if (tile) {
#pragma unroll
        for (int k4 = 0; k4 < 16; ++k4)
            wc[k4] = make_float4(W1[(k4 * 4 + 0) * 64 + lane],
                                 W1[(k4 * 4 + 1) * 64 + lane],
                                 W1[(k4 * 4 + 2) * 64 + lane],
                                 W1[(k4 * 4 + 3) * 64 + lane]);
        int rr = tid >> 4, c = tid & 15;
        int gn = base + rr;
        ((float4*)ft[rr])[c] = (gn < n_nodes) ? feat4[(size_t)gn * 16 + c]
                                              : make_float4(0.f, 0.f, 0.f, 0.f);
    }
    __syncthreads();                      // staging vmem drained here

    // atomic AFTER the drain (R13 mechanism): only outstanding vmem op during
    // the pure-LDS/VALU compute below; its sole consumer is the rank store.
    int r = 0;
    if (he) r = atomicAdd(&counts[(size_t)d * PAD], 1);

    if (tile) {
        for (int i = 0; i < 4; ++i) {
            int rr = w * 4 + i;
            int gn = base + rr;
            if (gn < n_nodes) {
                float acc = 0.f;
                const float4* row4 = (const float4*)ft[rr];
#pragma unroll
                for (int k4 = 0; k4 < 16; ++k4) {
                    float4 f = row4[k4];   // uniform address -> LDS broadcast
                    acc = fmaf(f.x, wc[k4].x,
                          fmaf(f.y, wc[k4].y,
                          fmaf(f.z, wc[k4].z,
                          fmaf(f.w, wc[k4].w, acc))));
                }
                unsigned hb = f2bf(acc);
                unsigned other = __shfl_xor((int)hb, 1, 64);
                if (!(lane & 1))
                    fW1b[(size_t)gn * 32 + (lane >> 1)] = hb | (other << 16);
            }
        }
    }
    if (he) rank[e] = r;                  // the ONLY consumer of the atomic
}

// ---------------- scan A: per-1024-chunk exclusive scan ----------------
__global__ void scan_phaseA(const int* __restrict__ counts, int* __restrict__ excl,
                            int* __restrict__ blocksums, int n) {
    __shared__ int lds[SCAN_B];
    int tid = threadIdx.x;
    int i = blockIdx.x * SCAN_B + tid;
    int v = (i < n) ? counts[(size_t)i * PAD] : 0;
    lds[tid] = v;
    __syncthreads();
    for (int off = 1; off < SCAN_B; off <<= 1) {
        int t = (tid >= off) ? lds[tid - off] : 0;
        __syncthreads();
        lds[tid] += t;
        __syncthreads();
    }
    if (i < n) excl[i] = lds[tid] - v;
    if (tid == SCAN_B - 1) blocksums[blockIdx.x] = lds[SCAN_B - 1];
}

// ------- scan BC (merged): every block redundantly prefixes bsums, applies -------
__global__ void scan_phaseBC(int* __restrict__ offs, const int* __restrict__ blocksums,
                             int nb, int n, int E) {
    __shared__ int pre[256];              // nb <= 98 for N=100k
    int tid = threadIdx.x;
    int v = (tid < nb) ? blocksums[tid] : 0;
    pre[tid] = v;
    __syncthreads();
    for (int off = 1; off < 256; off <<= 1) {
        int t = (tid >= off) ? pre[tid - off] : 0;
        __syncthreads();
        pre[tid] += t;
        __syncthreads();
    }
    int my = pre[tid] - v;                // exclusive prefix of chunk tid
    __syncthreads();
    pre[tid] = my;
    __syncthreads();
    int i = blockIdx.x * 256 + tid;
    if (i < n) offs[i] += pre[i / SCAN_B];
    else if (i == n) offs[n] = E;
}

// ---------------- fill: atomic-free via rank, int4 ----------------
__global__ void fill_rank_kernel(const int* __restrict__ src, const int* __restrict__ dst,
                                 const int* __restrict__ rank, const int* __restrict__ offs,
                                 int* __restrict__ ssort, int E) {
    int e0 = ((int)blockIdx.x * 256 + (int)threadIdx.x) * 4;
    if (e0 >= E) return;
    if (e0 + 3 < E) {
        int4 d = ((const int4*)dst)[e0 >> 2];
        int4 sr = ((const int4*)src)[e0 >> 2];
        int4 r = ((const int4*)rank)[e0 >> 2];
        ssort[offs[d.x] + r.x] = sr.x;
        ssort[offs[d.y] + r.y] = sr.y;
        ssort[offs[d.z] + r.z] = sr.z;
        ssort[offs[d.w] + r.w] = sr.w;
    } else {
        for (int e = e0; e < E; ++e)
            ssort[offs[dst[e]] + rank[e]] = src[e];
    }
}

// ------- layer1 tail: b1 + relu + compact dense2 (h@W2 -> p) -------
__device__ __forceinline__ void layer1_tail(float acc, int lane, int node,
                                            const float* __restrict__ b1,
                                            const float* __restrict__ W2,
                                            float* __restrict__ p)
{
    float h = fmaxf(acc + b1[lane], 0.f);
    int j = lane & 15, ks = lane >> 4;
    float pp = 0.f;
#pragma unroll
    for (int i = 0; i < 16; ++i) {
        int kk = ks * 16 + i;
        float hk = __shfl(h, kk, 64);          // broadcast h[kk] from lane kk
        pp = fmaf(hk, W2[kk * 16 + j], pp);
    }
    pp += __shfl_xor(pp, 16, 64);
    pp += __shfl_xor(pp, 32, 64);
    if (ks == 0) p[(size_t)node * 16 + j] = pp;
}

// ---------- layer1: gather bf16 fW1 rows, u32/lane, up to 16 edges in flight ----------
__global__ __launch_bounds__(256) void layer1_kernel(
    const unsigned* __restrict__ fW1b, const int* __restrict__ offs,
    const int* __restrict__ ssort, const float* __restrict__ b1,
    const float* __restrict__ W2, float* __restrict__ p, int n_nodes)
{
    int lane = threadIdx.x & 63;
    int w = threadIdx.x >> 6;
    int node = blockIdx.x * 4 + w;
    if (node >= n_nodes) return;            // no barriers below
    int beg = offs[node], end = offs[node + 1];
    int half = lane >> 5;                   // which edge of the pair
    int sl = lane & 31;                     // col pair -> cols 2sl, 2sl+1
    float ax = 0.f, ay = 0.f;
    int k = beg + half;
    for (; k + 14 < end; k += 16) {         // 16 edges in flight per wave
        int s0 = ssort[k],      s1 = ssort[k + 2],  s2 = ssort[k + 4],  s3 = ssort[k + 6];
        int s4 = ssort[k + 8],  s5 = ssort[k + 10], s6 = ssort[k + 12], s7 = ssort[k + 14];
        unsigned u0 = fW1b[(size_t)s0 * 32 + sl];
        unsigned u1 = fW1b[(size_t)s1 * 32 + sl];
        unsigned u2 = fW1b[(size_t)s2 * 32 + sl];
        unsigned u3 = fW1b[(size_t)s3 * 32 + sl];
        unsigned u4 = fW1b[(size_t)s4 * 32 + sl];
        unsigned u5 = fW1b[(size_t)s5 * 32 + sl];
        unsigned u6 = fW1b[(size_t)s6 * 32 + sl];
        unsigned u7 = fW1b[(size_t)s7 * 32 + sl];
        ax += (__uint_as_float(u0 << 16) + __uint_as_float(u1 << 16))
            + (__uint_as_float(u2 << 16) + __uint_as_float(u3 << 16))
            + (__uint_as_float(u4 << 16) + __uint_as_float(u5 << 16))
            + (__uint_as_float(u6 << 16) + __uint_as_float(u7 << 16));
        ay += (__uint_as_float(u0 & 0xffff0000u) + __uint_as_float(u1 & 0xffff0000u))
            + (__uint_as_float(u2 & 0xffff0000u) + __uint_as_float(u3 & 0xffff0000u))
            + (__uint_as_float(u4 & 0xffff0000u) + __uint_as_float(u5 & 0xffff0000u))
            + (__uint_as_float(u6 & 0xffff0000u) + __uint_as_float(u7 & 0xffff0000u));
    }
    for (; k + 6 < end; k += 8) {
        int s0 = ssort[k], s1 = ssort[k + 2], s2 = ssort[k + 4], s3 = ssort[k + 6];
        unsigned u0 = fW1b[(size_t)s0 * 32 + sl];
        unsigned u1 = fW1b[(size_t)s1 * 32 + sl];
        unsigned u2 = fW1b[(size_t)s2 * 32 + sl];
        unsigned u3 = fW1b[(size_t)s3 * 32 + sl];
        ax += (__uint_as_float(u0 << 16) + __uint_as_float(u1 << 16))
            + (__uint_as_float(u2 << 16) + __uint_as_float(u3 << 16));
        ay += (__uint_as_float(u0 & 0xffff0000u) + __uint_as_float(u1 & 0xffff0000u))
            + (__uint_as_float(u2 & 0xffff0000u) + __uint_as_float(u3 & 0xffff0000u));
    }
    for (; k < end; k += 2) {
        unsigned u = fW1b[(size_t)ssort[k] * 32 + sl];
        ax += __uint_as_float(u << 16);
        ay += __uint_as_float(u & 0xffff0000u);
    }
    ax += __shfl_xor(ax, 32, 64);
    ay += __shfl_xor(ay, 32, 64);
    float am = __shfl(ax, lane >> 1, 64);
    float bm = __shfl(ay, lane >> 1, 64);
    float acc = (lane & 1) ? bm : am;
    layer1_tail(acc, lane, node, b1, W2, p);
}

// ---------- layer2: wave/node, float4 per lane, 32 edges in flight ----------
__global__ __launch_bounds__(256) void layer2_kernel(
    const float4* __restrict__ p4, const int* __restrict__ offs,
    const int* __restrict__ ssort, const float* __restrict__ b2,
    float* __restrict__ out, int n_nodes)
{
    int lane = threadIdx.x & 63;
    int w = threadIdx.x >> 6;
    int node = blockIdx.x * 4 + w;
    if (node >= n_nodes) return;
    int slot = lane >> 2;   // edge slot 0..15
    int q = lane & 3;       // col quad -> cols 4q..4q+3
    int beg = offs[node], end = offs[node + 1];
    float a0 = 0.f, a1 = 0.f, a2 = 0.f, a3 = 0.f;
    int k = beg + slot;
    for (; k + 16 < end; k += 32) {     // 32 edges in flight
        int s0 = ssort[k], s1 = ssort[k + 16];
        float4 v0 = p4[(size_t)s0 * 4 + q];
        float4 v1 = p4[(size_t)s1 * 4 + q];
        a0 += v0.x + v1.x;
        a1 += v0.y + v1.y;
        a2 += v0.z + v1.z;
        a3 += v0.w + v1.w;
    }
    for (; k < end; k += 16) {
        float4 v = p4[(size_t)ssort[k] * 4 + q];
        a0 += v.x; a1 += v.y; a2 += v.z; a3 += v.w;
    }
#pragma unroll
    for (int dd = 4; dd <= 32; dd <<= 1) {
        a0 += __shfl_xor(a0, dd, 64);
        a1 += __shfl_xor(a1, dd, 64);
        a2 += __shfl_xor(a2, dd, 64);
        a3 += __shfl_xor(a3, dd, 64);
    }
    float4 bb = ((const float4*)b2)[q];
    float v0 = a0 + bb.x, v1 = a1 + bb.y, v2 = a2 + bb.z, v3 = a3 + bb.w;
    float m = fmaxf(fmaxf(v0, v1), fmaxf(v2, v3));
    m = fmaxf(m, __shfl_xor(m, 1, 64));
    m = fmaxf(m, __shfl_xor(m, 2, 64));
    float e0 = __expf(v0 - m), e1 = __expf(v1 - m);
    float e2 = __expf(v2 - m), e3 = __expf(v3 - m);
    float s = (e0 + e1) + (e2 + e3);
    s += __shfl_xor(s, 1, 64);
    s += __shfl_xor(s, 2, 64);
    if (slot == 0) {
        float inv = 1.f / s;
        float4 o; o.x = e0 * inv; o.y = e1 * inv; o.z = e2 * inv; o.w = e3 * inv;
        ((float4*)out)[(size_t)node * 4 + q] = o;
    }
}

extern "C" void kernel_launch(void* const* d_in, const int* in_sizes, int n_in,
                              void* d_out, int out_size, void* d_ws, size_t ws_size,
                              hipStream_t stream) {
    const float* feat = (const float*)d_in[0];
    const float* W1   = (const float*)d_in[1];
    const float* b1   = (const float*)d_in[2];
    const float* W2   = (const float*)d_in[3];
    const float* b2   = (const float*)d_in[4];
    const int*   src  = (const int*)d_in[5];
    const int*   dst  = (const int*)d_in[6];

    int N = in_sizes[0] / 64;
    int E = in_sizes[5];

    // layout (ints): counts 16N (aliased by p 16N after scan) | fW1b 32N |
    //                offs N+1 | bsums SCAN_B | ssort E | rank E   (~32.4MB)
    int*      counts = (int*)d_ws;
    float*    p      = (float*)d_ws;                 // counts dead after scanA
    unsigned* fW1b   = (unsigned*)(counts + (size_t)N * PAD);
    int*      offs   = (int*)(fW1b + (size_t)N * 32);
    int*      bsums  = offs + N + 1;
    int*      ssort  = bsums + SCAN_B;
    int*      rank   = ssort + E;
    float*    out    = (float*)d_out;

    int nb = (N + SCAN_B - 1) / SCAN_B;
    int histBlocks = (E + 255) / 256;
    int ntiles = (N + 15) / 16;                      // == histBlocks here
    int prepGrid = histBlocks > ntiles ? histBlocks : ntiles;

    hipMemsetAsync(counts, 0, (size_t)N * PAD * sizeof(int), stream);

    prep_kernel<<<prepGrid, 256, 0, stream>>>(
        (const float4*)feat, W1, fW1b, dst, counts, rank, N, E, ntiles);

    scan_phaseA<<<nb, SCAN_B, 0, stream>>>(counts, offs, bsums, N);
    scan_phaseBC<<<(N + 1 + 255) / 256, 256, 0, stream>>>(offs, bsums, nb, N, E);

    fill_rank_kernel<<<(E + 1023) / 1024, 256, 0, stream>>>(src, dst, rank, offs, ssort, E);

    layer1_kernel<<<(N + 3) / 4, 256, 0, stream>>>(fW1b, offs, ssort, b1, W2, p, N);
    layer2_kernel<<<(N + 3) / 4, 256, 0, stream>>>((const float4*)p, offs, ssort, b2, out, N);
}